// Round 1
// baseline (24.827 us; speedup 1.0000x reference)
//
#include <hip/hip_runtime.h>

// Dempster-Shafer Wasserstein-like distance, n=3 classes (C=4), FOCAL=1.
// Per pixel closed form:
//   h = x3/2, q = h*h/3
//   out[0]=0; out[7]=0
//   out[1]=(x0+h-1)^2+q      out[2]=(x1+h)^2+q
//   out[3]=(x0+x1+h-1)^2+q   out[4]=(x2+h)^2+q
//   out[5]=(x0+x2+h-1)^2+q   out[6]=(x1+x2+h)^2+q

__global__ __launch_bounds__(256) void wasserstein_ds_kernel(
    const float4* __restrict__ in,   // [npix] of (x0,x1,x2,x3)
    float4* __restrict__ out,        // [npix*2] (8 floats per pixel)
    int npix)
{
    int i = blockIdx.x * blockDim.x + threadIdx.x;
    if (i >= npix) return;

    float4 x = in[i];
    float h = 0.5f * x.w;
    float q = h * h * (1.0f / 3.0f);

    float b1 = x.x + h - 1.0f;            // s=1 (odd -> sum_x=1)
    float b2 = x.y + h;                   // s=2
    float b3 = x.x + x.y + h - 1.0f;      // s=3
    float b4 = x.z + h;                   // s=4
    float b5 = x.x + x.z + h - 1.0f;      // s=5
    float b6 = x.y + x.z + h;             // s=6

    float4 lo, hi;
    lo.x = 0.0f;
    lo.y = b1 * b1 + q;
    lo.z = b2 * b2 + q;
    lo.w = b3 * b3 + q;
    hi.x = b4 * b4 + q;
    hi.y = b5 * b5 + q;
    hi.z = b6 * b6 + q;
    hi.w = 0.0f;

    out[2 * i]     = lo;
    out[2 * i + 1] = hi;
}

extern "C" void kernel_launch(void* const* d_in, const int* in_sizes, int n_in,
                              void* d_out, int out_size, void* d_ws, size_t ws_size,
                              hipStream_t stream) {
    const float4* in = (const float4*)d_in[0];
    float4* out = (float4*)d_out;
    int npix = in_sizes[0] / 4;          // B*H*W = 1,916,928

    int block = 256;
    int grid = (npix + block - 1) / block;
    wasserstein_ds_kernel<<<grid, block, 0, stream>>>(in, out, npix);
}